// Round 5
// baseline (14722.676 us; speedup 1.0000x reference)
//
#include <hip/hip_runtime.h>

#define BB 64
#define TT 512
#define EE 512
#define HH 1024
#define NCLS 5
#define NWG 128

typedef __attribute__((ext_vector_type(8))) short bfrag;
typedef __attribute__((ext_vector_type(4))) float facc;

// ---- workspace layout (bytes) ----
#define XE_BYTES   ((size_t)TT * BB * EE * 2)        // 32 MB
#define FEAT_BYTES ((size_t)BB * HH * 4)             // 256 KB
#define SYNC_BYTES ((size_t)4096)
#define HBUF_FULL  ((size_t)TT * BB * HH * 2)        // 64 MB (full-T, never-reused addresses)
#define HBUF_SMALL ((size_t)2 * BB * HH * 2)         // 256 KB (double-buffer fallback)
#define PROBE_BYTES ((size_t)8192)

static __device__ __forceinline__ unsigned short f2bf(float f) {
  unsigned int u = __float_as_uint(f);
  u += 0x7fff + ((u >> 16) & 1);   // RNE
  return (unsigned short)(u >> 16);
}

// ---- coherent (cross-XCD) helpers ----
static __device__ __forceinline__ void st_u32_sys(unsigned int* p, unsigned int v) {
  asm volatile("global_store_dword %0, %1, off sc0 sc1" :: "v"(p), "v"(v) : "memory");
}
static __device__ __forceinline__ unsigned int ld_u32_sys(const unsigned int* p) {
  unsigned int r;
  asm volatile("global_load_dword %0, %1, off sc0 sc1\n\t"
               "s_waitcnt vmcnt(0)" : "=v"(r) : "v"(p) : "memory");
  return r;
}
static __device__ __forceinline__ void ld2_u32_sys(const unsigned int* p0,
                                                   const unsigned int* p1,
                                                   unsigned int& a, unsigned int& b) {
  asm volatile("global_load_dword %0, %2, off sc0 sc1\n\t"
               "global_load_dword %1, %3, off sc0 sc1\n\t"
               "s_waitcnt vmcnt(0)"
               : "=&v"(a), "=&v"(b) : "v"(p0), "v"(p1) : "memory");
}

// ---------------- kernel 1: embedding gather -> bf16 xe[t][b][e] ----------------
__global__ __launch_bounds__(256) void k_gather(const int* __restrict__ x,
                                                const float* __restrict__ emb,
                                                unsigned short* __restrict__ xe,
                                                int* __restrict__ sync,
                                                unsigned int* __restrict__ psync) {
  if (blockIdx.x == 0) {
    sync[threadIdx.x] = 0; sync[threadIdx.x + 256] = 0;
    if (psync) {
#pragma unroll
      for (int i = 0; i < 4; ++i) psync[threadIdx.x + 256 * i] = 0;
    }
  }
  int wave = (blockIdx.x * 256 + threadIdx.x) >> 6;  // 0..32767
  int lane = threadIdx.x & 63;
  int t = wave >> 6;
  int b = wave & 63;
  int tok = x[b * TT + t];
  const float* src = emb + (size_t)tok * EE + lane * 8;
  float4 f0 = ((const float4*)src)[0];
  float4 f1 = ((const float4*)src)[1];
  uint4 pk;
  pk.x = (unsigned)f2bf(f0.x) | ((unsigned)f2bf(f0.y) << 16);
  pk.y = (unsigned)f2bf(f0.z) | ((unsigned)f2bf(f0.w) << 16);
  pk.z = (unsigned)f2bf(f1.x) | ((unsigned)f2bf(f1.y) << 16);
  pk.w = (unsigned)f2bf(f1.z) | ((unsigned)f2bf(f1.w) << 16);
  *(uint4*)(xe + ((size_t)t * BB + b) * EE + lane * 8) = pk;
}

// ---------------- kernel 2: persistent LSTM recurrence (R3, unchanged) ----------------
template <bool FULLT>
__global__ __launch_bounds__(256, 1) void k_lstm(const float* __restrict__ W_ih,
                                                 const float* __restrict__ W_hh,
                                                 const float* __restrict__ b_ih,
                                                 const float* __restrict__ b_hh,
                                                 const unsigned short* __restrict__ xe,
                                                 unsigned short* __restrict__ hbuf,
                                                 float* __restrict__ feat,
                                                 int* __restrict__ sync) {
  __shared__ unsigned short Wlds[32][1544];
  __shared__ float bias_lds[32];

  const int w = blockIdx.x;
  const int tid = threadIdx.x;

  for (int idx = tid; idx < 32 * 512; idx += 256) {
    int r = idx >> 9, k = idx & 511;
    int R = (r >> 3) * 1024 + w * 8 + (r & 7);
    Wlds[r][k] = f2bf(W_ih[(size_t)R * EE + k]);
  }
  for (int idx = tid; idx < 32 * 1024; idx += 256) {
    int r = idx >> 10, k = idx & 1023;
    int R = (r >> 3) * 1024 + w * 8 + (r & 7);
    Wlds[r][512 + k] = f2bf(W_hh[(size_t)R * HH + k]);
  }
  if (tid < 32) {
    int R = (tid >> 3) * 1024 + w * 8 + (tid & 7);
    bias_lds[tid] = b_ih[R] + b_hh[R];
  }
  __syncthreads();

  const int lane = tid & 63;
  const int wm = tid >> 6;
  const int c15 = lane & 15;
  const int kq = lane >> 4;
  const int k0 = kq * 8;
  const int bA = wm * 16 + c15;

  const unsigned short* wl0 = &Wlds[c15][k0];
  const unsigned short* wl1 = &Wlds[16 + c15][k0];
  const float bias0 = bias_lds[c15];
  const float bias1 = bias_lds[16 + c15];

  float cst[4]  = {0.f, 0.f, 0.f, 0.f};
  float hmax[4] = {-1e30f, -1e30f, -1e30f, -1e30f};

  unsigned int* flags = (unsigned int*)sync;

  const size_t xe_lane = (size_t)bA * EE + k0;
  const size_t h_lane  = (size_t)bA * HH + k0;
  const unsigned int* fp0 = flags + lane;
  const unsigned int* fp1 = flags + 64 + lane;

  for (int t = 0; t < TT; ++t) {
    facc a0 = {0.f,0.f,0.f,0.f}, a1 = a0, a2 = a0, a3 = a0;
    const unsigned short* xet = xe + (size_t)t * (BB * EE) + xe_lane;

#pragma unroll 4
    for (int kk = 0; kk < 16; kk += 2) {
      bfrag A  = *(const bfrag*)(xet + kk * 32);
      bfrag B0 = *(const bfrag*)(wl0 + kk * 32);
      bfrag B1 = *(const bfrag*)(wl1 + kk * 32);
      a0 = __builtin_amdgcn_mfma_f32_16x16x32_bf16(A, B0, a0, 0, 0, 0);
      a2 = __builtin_amdgcn_mfma_f32_16x16x32_bf16(A, B1, a2, 0, 0, 0);
      bfrag A2  = *(const bfrag*)(xet + kk * 32 + 32);
      bfrag B0b = *(const bfrag*)(wl0 + kk * 32 + 32);
      bfrag B1b = *(const bfrag*)(wl1 + kk * 32 + 32);
      a1 = __builtin_amdgcn_mfma_f32_16x16x32_bf16(A2, B0b, a1, 0, 0, 0);
      a3 = __builtin_amdgcn_mfma_f32_16x16x32_bf16(A2, B1b, a3, 0, 0, 0);
    }

    if (t > 0) {
      unsigned int fa, fb;
      do {
        ld2_u32_sys(fp0, fp1, fa, fb);
      } while (__any((int)(min(fa, fb) < (unsigned)t)));
      __builtin_amdgcn_sched_barrier(0);

      if constexpr (FULLT) {
        const unsigned short* hp = hbuf + (size_t)t * (BB * HH) + h_lane;
#pragma unroll 4
        for (int kk = 0; kk < 32; kk += 2) {
          bfrag A  = *(const bfrag*)(hp + kk * 32);
          bfrag B0 = *(const bfrag*)(wl0 + 512 + kk * 32);
          bfrag B1 = *(const bfrag*)(wl1 + 512 + kk * 32);
          a0 = __builtin_amdgcn_mfma_f32_16x16x32_bf16(A, B0, a0, 0, 0, 0);
          a2 = __builtin_amdgcn_mfma_f32_16x16x32_bf16(A, B1, a2, 0, 0, 0);
          bfrag A2  = *(const bfrag*)(hp + (kk + 1) * 32);
          bfrag B0b = *(const bfrag*)(wl0 + 512 + (kk + 1) * 32);
          bfrag B1b = *(const bfrag*)(wl1 + 512 + (kk + 1) * 32);
          a1 = __builtin_amdgcn_mfma_f32_16x16x32_bf16(A2, B0b, a1, 0, 0, 0);
          a3 = __builtin_amdgcn_mfma_f32_16x16x32_bf16(A2, B1b, a3, 0, 0, 0);
        }
      } else {
        const unsigned short* hp = hbuf + ((t & 1) ? (size_t)(BB * HH) : 0) + h_lane;
        bfrag hA[32];
#pragma unroll
        for (int i = 0; i < 32; ++i)
          asm volatile("global_load_dwordx4 %0, %1, off sc0 sc1"
                       : "=v"(hA[i]) : "v"(hp + i * 32));
        __builtin_amdgcn_sched_barrier(0);
        asm volatile("s_waitcnt vmcnt(0)" ::: "memory");
        __builtin_amdgcn_sched_barrier(0);
#pragma unroll
        for (int kk = 0; kk < 32; kk += 2) {
          bfrag B0 = *(const bfrag*)(wl0 + 512 + kk * 32);
          bfrag B1 = *(const bfrag*)(wl1 + 512 + kk * 32);
          a0 = __builtin_amdgcn_mfma_f32_16x16x32_bf16(hA[kk], B0, a0, 0, 0, 0);
          a2 = __builtin_amdgcn_mfma_f32_16x16x32_bf16(hA[kk], B1, a2, 0, 0, 0);
          bfrag B0b = *(const bfrag*)(wl0 + 512 + (kk + 1) * 32);
          bfrag B1b = *(const bfrag*)(wl1 + 512 + (kk + 1) * 32);
          a1 = __builtin_amdgcn_mfma_f32_16x16x32_bf16(hA[kk + 1], B0b, a1, 0, 0, 0);
          a3 = __builtin_amdgcn_mfma_f32_16x16x32_bf16(hA[kk + 1], B1b, a3, 0, 0, 0);
        }
      }
    }

    facc X = a0 + a1;
    facc Y = a2 + a3;
    unsigned int hb[4];
#pragma unroll
    for (int j = 0; j < 4; ++j) {
      float xv = X[j] + bias0;
      float yv = Y[j] + bias1;
      float xs = __shfl_xor(xv, 8, 64);
      float ys = __shfl_xor(yv, 8, 64);
      bool lo = (c15 < 8);
      float vi = lo ? xv : xs;
      float vf = lo ? xs : xv;
      float vg = lo ? yv : ys;
      float vo = lo ? ys : yv;
      float sf = 1.f / (1.f + __expf(-vf));
      float si = 1.f / (1.f + __expf(-vi));
      float eg = __expf(-2.f * fabsf(vg));
      float tg = copysignf((1.f - eg) / (1.f + eg), vg);
      float cc = sf * cst[j] + si * tg;
      cst[j] = cc;
      float so = 1.f / (1.f + __expf(-vo));
      float ec = __expf(-2.f * fabsf(cc));
      float tc = copysignf((1.f - ec) / (1.f + ec), cc);
      float hh = so * tc;
      hmax[j] = fmaxf(hmax[j], hh);
      hb[j] = f2bf(hh);
    }

    if (t < TT - 1) {
      unsigned int* hn32;
      if constexpr (FULLT)
        hn32 = (unsigned int*)(hbuf + (size_t)(t + 1) * (BB * HH));
      else
        hn32 = (unsigned int*)(hbuf + ((t & 1) ? 0 : (size_t)(BB * HH)));
#pragma unroll
      for (int j = 0; j < 4; ++j) {
        unsigned int part = (unsigned int)__shfl_xor((int)hb[j], 1, 64);
        if ((c15 & 1) == 0 && c15 < 8) {
          unsigned int v = (hb[j] & 0xffffu) | (part << 16);
          unsigned int* p = hn32 + (size_t)(wm * 16 + kq * 4 + j) * (HH / 2)
                                 + w * 4 + (c15 >> 1);
          st_u32_sys(p, v);
        }
      }
      asm volatile("s_waitcnt vmcnt(0)" ::: "memory");
      __syncthreads();
      if (tid == 0) st_u32_sys(flags + w, (unsigned)(t + 1));
    }
  }

  if (c15 < 8) {
    int jh = w * 8 + c15;
#pragma unroll
    for (int j = 0; j < 4; ++j)
      feat[(size_t)(wm * 16 + kq * 4 + j) * HH + jh] = hmax[j];
  }
}

// ---------------- kernel 3: tiny FC ----------------
__global__ __launch_bounds__(64) void k_fc(const float* __restrict__ feat,
                                           const float* __restrict__ W_fc,
                                           const float* __restrict__ b_fc,
                                           float* __restrict__ out) {
  int b = blockIdx.x, cls = blockIdx.y;
  int lane = threadIdx.x;
  const float* f  = feat + (size_t)b * HH;
  const float* wr = W_fc + (size_t)cls * HH;
  float s = 0.f;
  for (int k = lane; k < HH; k += 64) s = fmaf(f[k], wr[k], s);
#pragma unroll
  for (int off = 32; off > 0; off >>= 1) s += __shfl_down(s, off, 64);
  if (lane == 0) out[b * NCLS + cls] = s + b_fc[cls];
}

// ================= diagnostic probes (read via rocprof dispatch rows) =================

// p_ws: Workgroup_Size column encodes ws_size in MB; fixed ~200us spin keeps it in top-5.
__global__ void p_ws() {
  unsigned long long r0 = __builtin_amdgcn_s_memrealtime();
  while (__builtin_amdgcn_s_memrealtime() - r0 < 20000ULL) {}
}

// p_clk: 2.0e6 dependent SALU ops on 1 wave per WG (near-idle chip).
// dur ~= 2.1e6 cyc / SCLK:  ~0.9ms @2.4GHz;  >=2ms => downclocking during idle-ish kernels.
__global__ __launch_bounds__(64) void p_clk() {
  unsigned a = 0; int n = 2000000;
  asm volatile(
      "1:\n\t"
      "s_add_i32 %0, %0, 1\n\t" "s_add_i32 %0, %0, 1\n\t"
      "s_add_i32 %0, %0, 1\n\t" "s_add_i32 %0, %0, 1\n\t"
      "s_add_i32 %0, %0, 1\n\t" "s_add_i32 %0, %0, 1\n\t"
      "s_add_i32 %0, %0, 1\n\t" "s_add_i32 %0, %0, 1\n\t"
      "s_add_i32 %0, %0, 1\n\t" "s_add_i32 %0, %0, 1\n\t"
      "s_add_i32 %0, %0, 1\n\t" "s_add_i32 %0, %0, 1\n\t"
      "s_add_i32 %0, %0, 1\n\t" "s_add_i32 %0, %0, 1\n\t"
      "s_add_i32 %0, %0, 1\n\t" "s_add_i32 %0, %0, 1\n\t"
      "s_add_i32 %1, %1, -16\n\t"
      "s_cmp_gt_i32 %1, 0\n\t"
      "s_cbranch_scc1 1b\n\t"
      : "+s"(a), "+s"(n) :: "scc");
  asm volatile("" :: "s"(a));
}

// p_bar: exact replica of k_lstm's per-step flag round, x512, no compute.
// dur/512 = pure barrier latency.
__global__ __launch_bounds__(256) void p_bar(unsigned int* flags) {
  const int w = blockIdx.x;
  const int tid = threadIdx.x;
  const int lane = tid & 63;
  const unsigned int* fp0 = flags + lane;
  const unsigned int* fp1 = flags + 64 + lane;
  for (int t = 1; t <= 512; ++t) {
    __syncthreads();
    if (tid == 0) st_u32_sys(flags + w, (unsigned)t);
    unsigned int fa, fb;
    do {
      ld2_u32_sys(fp0, fp1, fa, fb);
    } while (__any((int)(min(fa, fb) < (unsigned)t)));
  }
}

// p_xcc: OR of (1<<XCC_ID) over all 128 WGs; dur_us ~= 300 + 10*mask.
// mask==255 => XCC_ID readable & WGs span 8 XCDs.
__global__ __launch_bounds__(64) void p_xcc(unsigned int* scr) {
  if (threadIdx.x == 0) {
    unsigned int v;
    asm volatile("s_getreg_b32 %0, hwreg(HW_REG_XCC_ID)" : "=s"(v));
    __hip_atomic_fetch_or(scr, 1u << (v & 7), __ATOMIC_RELAXED, __HIP_MEMORY_SCOPE_AGENT);
  }
  if (blockIdx.x == 0 && threadIdx.x == 0) {
    unsigned long long r0 = __builtin_amdgcn_s_memrealtime();
    while (__builtin_amdgcn_s_memrealtime() - r0 < 3000ULL) {}
    unsigned int m = ld_u32_sys(scr);
    unsigned long long tgt = 30000ULL + (unsigned long long)m * 1000ULL;
    while (__builtin_amdgcn_s_memrealtime() - r0 < tgt) {}
  }
}

extern "C" void kernel_launch(void* const* d_in, const int* in_sizes, int n_in,
                              void* d_out, int out_size, void* d_ws, size_t ws_size,
                              hipStream_t stream) {
  const int*   x    = (const int*)d_in[0];
  const float* emb  = (const float*)d_in[1];
  const float* W_ih = (const float*)d_in[2];
  const float* W_hh = (const float*)d_in[3];
  const float* b_ih = (const float*)d_in[4];
  const float* b_hh = (const float*)d_in[5];
  const float* W_fc = (const float*)d_in[6];
  const float* b_fc = (const float*)d_in[7];
  float* out = (float*)d_out;

  char* ws = (char*)d_ws;
  unsigned short* xe   = (unsigned short*)(ws);
  float*          feat = (float*)(ws + XE_BYTES);
  int*            sync = (int*)(ws + XE_BYTES + FEAT_BYTES);
  unsigned short* hbuf = (unsigned short*)(ws + XE_BYTES + FEAT_BYTES + SYNC_BYTES);

  const size_t base = XE_BYTES + FEAT_BYTES + SYNC_BYTES;
  const bool full = (ws_size >= base + HBUF_FULL + PROBE_BYTES);
  const size_t poff = base + (full ? HBUF_FULL : HBUF_SMALL);
  const bool probes = (ws_size >= poff + PROBE_BYTES);
  unsigned int* psync = probes ? (unsigned int*)(ws + poff) : nullptr;

  k_gather<<<dim3(8192), dim3(256), 0, stream>>>(x, emb, xe, sync, psync);
  if (full)
    k_lstm<true><<<dim3(NWG), dim3(256), 0, stream>>>(W_ih, W_hh, b_ih, b_hh, xe, hbuf, feat, sync);
  else
    k_lstm<false><<<dim3(NWG), dim3(256), 0, stream>>>(W_ih, W_hh, b_ih, b_hh, xe, hbuf, feat, sync);
  k_fc<<<dim3(BB, NCLS), dim3(64), 0, stream>>>(feat, W_fc, b_fc, out);

  // ---- probes (diagnostic; read their rows in the rocprof table) ----
  unsigned int wsmb = (unsigned int)(ws_size >> 20);
  if (wsmb < 1) wsmb = 1;
  if (wsmb > 1024) wsmb = 1024;
  p_ws<<<dim3(1), dim3(wsmb), 0, stream>>>();
  p_clk<<<dim3(NWG), dim3(64), 0, stream>>>();
  if (probes) {
    p_bar<<<dim3(NWG), dim3(256), 0, stream>>>(psync);          // flags at psync[0..127]
    p_xcc<<<dim3(NWG), dim3(64), 0, stream>>>(psync + 512);     // mask at psync[512]
  }
}

// Round 6
// 11019.018 us; speedup vs baseline: 1.3361x; 1.3361x over previous
//
#include <hip/hip_runtime.h>

#define BB 64
#define TT 512
#define EE 512
#define HH 1024
#define NCLS 5
#define NWG 128

typedef __attribute__((ext_vector_type(8))) short bfrag;
typedef __attribute__((ext_vector_type(4))) float facc;

// ---- workspace layout (bytes) ----
#define XE_BYTES   ((size_t)TT * BB * EE * 2)        // 32 MB
#define FEAT_BYTES ((size_t)BB * HH * 4)             // 256 KB
#define SYNC_BYTES ((size_t)8192)                    // 128 spread flags, 64B apart
#define HBUF_FULL  ((size_t)TT * BB * HH * 2)        // 64 MB (full-T, never-reused addresses)
#define HBUF_SMALL ((size_t)2 * BB * HH * 2)         // 256 KB (double-buffer fallback)

static __device__ __forceinline__ unsigned short f2bf(float f) {
  unsigned int u = __float_as_uint(f);
  u += 0x7fff + ((u >> 16) & 1);   // RNE
  return (unsigned short)(u >> 16);
}

// ---- coherent (cross-XCD, MALL-level) helpers ----
static __device__ __forceinline__ void st_u32_sys(unsigned int* p, unsigned int v) {
  asm volatile("global_store_dword %0, %1, off sc0 sc1" :: "v"(p), "v"(v) : "memory");
}
static __device__ __forceinline__ void ld2_u32_sys(const unsigned int* p0,
                                                   const unsigned int* p1,
                                                   unsigned int& a, unsigned int& b) {
  asm volatile("global_load_dword %0, %2, off sc0 sc1\n\t"
               "global_load_dword %1, %3, off sc0 sc1\n\t"
               "s_waitcnt vmcnt(0)"
               : "=&v"(a), "=&v"(b) : "v"(p0), "v"(p1) : "memory");
}

// ---------------- kernel 1: embedding gather -> bf16 xe[t][b][e] ----------------
__global__ __launch_bounds__(256) void k_gather(const int* __restrict__ x,
                                                const float* __restrict__ emb,
                                                unsigned short* __restrict__ xe,
                                                int* __restrict__ sync) {
  if (blockIdx.x == 0) {
#pragma unroll
    for (int i = 0; i < 8; ++i) sync[threadIdx.x + 256 * i] = 0;  // zero 8KB flag region
  }
  int wave = (blockIdx.x * 256 + threadIdx.x) >> 6;  // 0..32767
  int lane = threadIdx.x & 63;
  int t = wave >> 6;
  int b = wave & 63;
  int tok = x[b * TT + t];
  const float* src = emb + (size_t)tok * EE + lane * 8;
  float4 f0 = ((const float4*)src)[0];
  float4 f1 = ((const float4*)src)[1];
  uint4 pk;
  pk.x = (unsigned)f2bf(f0.x) | ((unsigned)f2bf(f0.y) << 16);
  pk.y = (unsigned)f2bf(f0.z) | ((unsigned)f2bf(f0.w) << 16);
  pk.z = (unsigned)f2bf(f1.x) | ((unsigned)f2bf(f1.y) << 16);
  pk.w = (unsigned)f2bf(f1.z) | ((unsigned)f2bf(f1.w) << 16);
  *(uint4*)(xe + ((size_t)t * BB + b) * EE + lane * 8) = pk;
}

// ---------------- kernel 2: persistent LSTM recurrence ----------------
// 128 WGs x 256 threads. WG w owns h indices [w*8, w*8+8): 32 rows of [W_ih|W_hh] in LDS.
// Barrier: spread flags (1 per 64B line) stored sc0sc1; ONE polling wave per WG with
// s_sleep backoff (congestion fix); no aggregation hop.
template <bool FULLT>
__global__ __launch_bounds__(256, 1) void k_lstm(const float* __restrict__ W_ih,
                                                 const float* __restrict__ W_hh,
                                                 const float* __restrict__ b_ih,
                                                 const float* __restrict__ b_hh,
                                                 const unsigned short* __restrict__ xe,
                                                 unsigned short* __restrict__ hbuf,
                                                 float* __restrict__ feat,
                                                 int* __restrict__ sync) {
  __shared__ unsigned short Wlds[32][1544];  // stride 772 words = 4 banks mod 32
  __shared__ float bias_lds[32];

  const int w = blockIdx.x;
  const int tid = threadIdx.x;
  unsigned int* sy = (unsigned int*)sync;

  for (int idx = tid; idx < 32 * 512; idx += 256) {
    int r = idx >> 9, k = idx & 511;
    int R = (r >> 3) * 1024 + w * 8 + (r & 7);
    Wlds[r][k] = f2bf(W_ih[(size_t)R * EE + k]);
  }
  for (int idx = tid; idx < 32 * 1024; idx += 256) {
    int r = idx >> 10, k = idx & 1023;
    int R = (r >> 3) * 1024 + w * 8 + (r & 7);
    Wlds[r][512 + k] = f2bf(W_hh[(size_t)R * HH + k]);
  }
  if (tid < 32) {
    int R = (tid >> 3) * 1024 + w * 8 + (tid & 7);
    bias_lds[tid] = b_ih[R] + b_hh[R];
  }
  __syncthreads();

  // One-time wholesale acquire invalidate: drop any stale/poisoned clean L1/L2 lines
  // (harness poisons ws between the correctness call and timed replays). Cheap at n=1/launch.
  { int dummy = 0; (void)__hip_atomic_load(&dummy, __ATOMIC_ACQUIRE, __HIP_MEMORY_SCOPE_SYSTEM); }
  __syncthreads();

  const int lane = tid & 63;
  const int wm = tid >> 6;
  const int c15 = lane & 15;
  const int kq = lane >> 4;
  const int k0 = kq * 8;
  const int bA = wm * 16 + c15;

  const unsigned short* wl0 = &Wlds[c15][k0];
  const unsigned short* wl1 = &Wlds[16 + c15][k0];
  const float bias0 = bias_lds[c15];
  const float bias1 = bias_lds[16 + c15];

  float cst[4]  = {0.f, 0.f, 0.f, 0.f};
  float hmax[4] = {-1e30f, -1e30f, -1e30f, -1e30f};

  const size_t xe_lane = (size_t)bA * EE + k0;
  const size_t h_lane  = (size_t)bA * HH + k0;
  // spread flags: flag[w] at sy[16*w] (64B apart)
  const unsigned int* q0 = sy + 16 * lane;
  const unsigned int* q1 = sy + 16 * (lane + 64);

  for (int t = 0; t < TT; ++t) {
    facc a0 = {0.f,0.f,0.f,0.f}, a1 = a0, a2 = a0, a3 = a0;
    const unsigned short* xet = xe + (size_t)t * (BB * EE) + xe_lane;

    // ---- xe-part (h-independent): overlaps producers' flag propagation ----
#pragma unroll 4
    for (int kk = 0; kk < 16; kk += 2) {
      bfrag A  = *(const bfrag*)(xet + kk * 32);
      bfrag B0 = *(const bfrag*)(wl0 + kk * 32);
      bfrag B1 = *(const bfrag*)(wl1 + kk * 32);
      a0 = __builtin_amdgcn_mfma_f32_16x16x32_bf16(A, B0, a0, 0, 0, 0);
      a2 = __builtin_amdgcn_mfma_f32_16x16x32_bf16(A, B1, a2, 0, 0, 0);
      bfrag A2  = *(const bfrag*)(xet + kk * 32 + 32);
      bfrag B0b = *(const bfrag*)(wl0 + kk * 32 + 32);
      bfrag B1b = *(const bfrag*)(wl1 + kk * 32 + 32);
      a1 = __builtin_amdgcn_mfma_f32_16x16x32_bf16(A2, B0b, a1, 0, 0, 0);
      a3 = __builtin_amdgcn_mfma_f32_16x16x32_bf16(A2, B1b, a3, 0, 0, 0);
    }

    if (t > 0) {
      // ---- barrier wait: wave0 only, spread lines, s_sleep backoff ----
      if (tid < 64) {
        unsigned int fa, fb;
        for (;;) {
          ld2_u32_sys(q0, q1, fa, fb);
          if (!__any((int)(min(fa, fb) < (unsigned)t))) break;
          __builtin_amdgcn_s_sleep(2);
        }
      }
      __syncthreads();

      if constexpr (FULLT) {
        // plain cached loads from never-before-touched addresses (L2-shareable)
        const unsigned short* hp = hbuf + (size_t)t * (BB * HH) + h_lane;
#pragma unroll 4
        for (int kk = 0; kk < 32; kk += 2) {
          bfrag A  = *(const bfrag*)(hp + kk * 32);
          bfrag B0 = *(const bfrag*)(wl0 + 512 + kk * 32);
          bfrag B1 = *(const bfrag*)(wl1 + 512 + kk * 32);
          a0 = __builtin_amdgcn_mfma_f32_16x16x32_bf16(A, B0, a0, 0, 0, 0);
          a2 = __builtin_amdgcn_mfma_f32_16x16x32_bf16(A, B1, a2, 0, 0, 0);
          bfrag A2  = *(const bfrag*)(hp + (kk + 1) * 32);
          bfrag B0b = *(const bfrag*)(wl0 + 512 + (kk + 1) * 32);
          bfrag B1b = *(const bfrag*)(wl1 + 512 + (kk + 1) * 32);
          a1 = __builtin_amdgcn_mfma_f32_16x16x32_bf16(A2, B0b, a1, 0, 0, 0);
          a3 = __builtin_amdgcn_mfma_f32_16x16x32_bf16(A2, B1b, a3, 0, 0, 0);
        }
      } else {
        const unsigned short* hp = hbuf + ((t & 1) ? (size_t)(BB * HH) : 0) + h_lane;
        bfrag hA[32];
#pragma unroll
        for (int i = 0; i < 32; ++i)
          asm volatile("global_load_dwordx4 %0, %1, off sc0 sc1"
                       : "=v"(hA[i]) : "v"(hp + i * 32));
        __builtin_amdgcn_sched_barrier(0);
        asm volatile("s_waitcnt vmcnt(0)" ::: "memory");
        __builtin_amdgcn_sched_barrier(0);
#pragma unroll
        for (int kk = 0; kk < 32; kk += 2) {
          bfrag B0 = *(const bfrag*)(wl0 + 512 + kk * 32);
          bfrag B1 = *(const bfrag*)(wl1 + 512 + kk * 32);
          a0 = __builtin_amdgcn_mfma_f32_16x16x32_bf16(hA[kk], B0, a0, 0, 0, 0);
          a2 = __builtin_amdgcn_mfma_f32_16x16x32_bf16(hA[kk], B1, a2, 0, 0, 0);
          bfrag B0b = *(const bfrag*)(wl0 + 512 + (kk + 1) * 32);
          bfrag B1b = *(const bfrag*)(wl1 + 512 + (kk + 1) * 32);
          a1 = __builtin_amdgcn_mfma_f32_16x16x32_bf16(hA[kk + 1], B0b, a1, 0, 0, 0);
          a3 = __builtin_amdgcn_mfma_f32_16x16x32_bf16(hA[kk + 1], B1b, a3, 0, 0, 0);
        }
      }
    }

    facc X = a0 + a1;
    facc Y = a2 + a3;
    unsigned int hb[4];
#pragma unroll
    for (int j = 0; j < 4; ++j) {
      float xv = X[j] + bias0;
      float yv = Y[j] + bias1;
      float xs = __shfl_xor(xv, 8, 64);
      float ys = __shfl_xor(yv, 8, 64);
      bool lo = (c15 < 8);
      float vi = lo ? xv : xs;
      float vf = lo ? xs : xv;
      float vg = lo ? yv : ys;
      float vo = lo ? ys : yv;
      float sf = 1.f / (1.f + __expf(-vf));
      float si = 1.f / (1.f + __expf(-vi));
      float eg = __expf(-2.f * fabsf(vg));
      float tg = copysignf((1.f - eg) / (1.f + eg), vg);
      float cc = sf * cst[j] + si * tg;
      cst[j] = cc;
      float so = 1.f / (1.f + __expf(-vo));
      float ec = __expf(-2.f * fabsf(cc));
      float tc = copysignf((1.f - ec) / (1.f + ec), cc);
      float hh = so * tc;
      hmax[j] = fmaxf(hmax[j], hh);
      hb[j] = f2bf(hh);
    }

    if (t < TT - 1) {
      unsigned int* hn32;
      if constexpr (FULLT)
        hn32 = (unsigned int*)(hbuf + (size_t)(t + 1) * (BB * HH));
      else
        hn32 = (unsigned int*)(hbuf + ((t & 1) ? 0 : (size_t)(BB * HH)));
#pragma unroll
      for (int j = 0; j < 4; ++j) {
        unsigned int part = (unsigned int)__shfl_xor((int)hb[j], 1, 64);
        if ((c15 & 1) == 0 && c15 < 8) {
          unsigned int v = (hb[j] & 0xffffu) | (part << 16);
          unsigned int* p = hn32 + (size_t)(wm * 16 + kq * 4 + j) * (HH / 2)
                                 + w * 4 + (c15 >> 1);
          st_u32_sys(p, v);
        }
      }
      asm volatile("s_waitcnt vmcnt(0)" ::: "memory");  // h at MALL before flag
      __syncthreads();
      if (tid == 0) st_u32_sys(sy + 16 * w, (unsigned)(t + 1));  // spread flag
    }
  }

  if (c15 < 8) {
    int jh = w * 8 + c15;
#pragma unroll
    for (int j = 0; j < 4; ++j)
      feat[(size_t)(wm * 16 + kq * 4 + j) * HH + jh] = hmax[j];
  }
}

// ---------------- kernel 3: tiny FC ----------------
__global__ __launch_bounds__(64) void k_fc(const float* __restrict__ feat,
                                           const float* __restrict__ W_fc,
                                           const float* __restrict__ b_fc,
                                           float* __restrict__ out) {
  int b = blockIdx.x, cls = blockIdx.y;
  int lane = threadIdx.x;
  const float* f  = feat + (size_t)b * HH;
  const float* wr = W_fc + (size_t)cls * HH;
  float s = 0.f;
  for (int k = lane; k < HH; k += 64) s = fmaf(f[k], wr[k], s);
#pragma unroll
  for (int off = 32; off > 0; off >>= 1) s += __shfl_down(s, off, 64);
  if (lane == 0) out[b * NCLS + cls] = s + b_fc[cls];
}

// ---- p_full: duration encodes which h-path ran (6.0 ms = FULLT, 5.2 ms = fallback).
// Will own the top-5 table; k_lstm dur = total - p_full - ~45us.
__global__ __launch_bounds__(64) void p_full(int full) {
  if (threadIdx.x == 0) {
    unsigned long long r0 = __builtin_amdgcn_s_memrealtime();
    unsigned long long tgt = full ? 600000ULL : 520000ULL;  // 100 MHz realtime ticks
    while (__builtin_amdgcn_s_memrealtime() - r0 < tgt) {}
  }
}

extern "C" void kernel_launch(void* const* d_in, const int* in_sizes, int n_in,
                              void* d_out, int out_size, void* d_ws, size_t ws_size,
                              hipStream_t stream) {
  const int*   x    = (const int*)d_in[0];
  const float* emb  = (const float*)d_in[1];
  const float* W_ih = (const float*)d_in[2];
  const float* W_hh = (const float*)d_in[3];
  const float* b_ih = (const float*)d_in[4];
  const float* b_hh = (const float*)d_in[5];
  const float* W_fc = (const float*)d_in[6];
  const float* b_fc = (const float*)d_in[7];
  float* out = (float*)d_out;

  char* ws = (char*)d_ws;
  unsigned short* xe   = (unsigned short*)(ws);
  float*          feat = (float*)(ws + XE_BYTES);
  int*            sync = (int*)(ws + XE_BYTES + FEAT_BYTES);
  unsigned short* hbuf = (unsigned short*)(ws + XE_BYTES + FEAT_BYTES + SYNC_BYTES);

  const size_t base = XE_BYTES + FEAT_BYTES + SYNC_BYTES;
  const bool full = (ws_size >= base + HBUF_FULL);

  k_gather<<<dim3(8192), dim3(256), 0, stream>>>(x, emb, xe, sync);
  if (full)
    k_lstm<true><<<dim3(NWG), dim3(256), 0, stream>>>(W_ih, W_hh, b_ih, b_hh, xe, hbuf, feat, sync);
  else
    k_lstm<false><<<dim3(NWG), dim3(256), 0, stream>>>(W_ih, W_hh, b_ih, b_hh, xe, hbuf, feat, sync);
  k_fc<<<dim3(BB, NCLS), dim3(64), 0, stream>>>(feat, W_fc, b_fc, out);
  p_full<<<dim3(1), dim3(64), 0, stream>>>(full ? 1 : 0);
}

// Round 9
// 5064.444 us; speedup vs baseline: 2.9071x; 2.1758x over previous
//
#include <hip/hip_runtime.h>

#define BB 64
#define TT 512
#define EE 512
#define HH 1024
#define NCLS 5
#define NWG 128

typedef __attribute__((ext_vector_type(8))) short bfrag;
typedef __attribute__((ext_vector_type(4))) float facc;
typedef __attribute__((ext_vector_type(4))) unsigned int u32x4;

// ---- workspace layout (bytes) ----
#define XE_BYTES   ((size_t)TT * BB * EE * 2)        // 32 MB
#define FEAT_BYTES ((size_t)BB * HH * 4)             // 256 KB
#define SYNC_BYTES ((size_t)8192)                    // 128 spread flags, 64B apart
#define HBUF_FULL  ((size_t)TT * BB * HH * 2)        // 64 MB (full-T, never-reused addresses)

static __device__ __forceinline__ unsigned short f2bf(float f) {
  unsigned int u = __float_as_uint(f);
  u += 0x7fff + ((u >> 16) & 1);   // RNE
  return (unsigned short)(u >> 16);
}

// ---- coherent (cross-XCD, MALL-level) helpers ----
static __device__ __forceinline__ void st_u32_sys(unsigned int* p, unsigned int v) {
  asm volatile("global_store_dword %0, %1, off sc0 sc1" :: "v"(p), "v"(v) : "memory");
}
static __device__ __forceinline__ void st_u32x4_sys(u32x4* p, u32x4 v) {
  asm volatile("global_store_dwordx4 %0, %1, off sc0 sc1" :: "v"(p), "v"(v) : "memory");
}
static __device__ __forceinline__ void ld2_u32_sys(const unsigned int* p0,
                                                   const unsigned int* p1,
                                                   unsigned int& a, unsigned int& b) {
  asm volatile("global_load_dword %0, %2, off sc0 sc1\n\t"
               "global_load_dword %1, %3, off sc0 sc1\n\t"
               "s_waitcnt vmcnt(0)"
               : "=&v"(a), "=&v"(b) : "v"(p0), "v"(p1) : "memory");
}

// ---------------- kernel 1: embedding gather -> bf16 xe[t][b][e] ----------------
__global__ __launch_bounds__(256) void k_gather(const int* __restrict__ x,
                                                const float* __restrict__ emb,
                                                unsigned short* __restrict__ xe,
                                                int* __restrict__ sync) {
  if (blockIdx.x == 0) {
#pragma unroll
    for (int i = 0; i < 8; ++i) sync[threadIdx.x + 256 * i] = 0;  // zero 8KB flag region
  }
  int wave = (blockIdx.x * 256 + threadIdx.x) >> 6;  // 0..32767
  int lane = threadIdx.x & 63;
  int t = wave >> 6;
  int b = wave & 63;
  int tok = x[b * TT + t];
  const float* src = emb + (size_t)tok * EE + lane * 8;
  float4 f0 = ((const float4*)src)[0];
  float4 f1 = ((const float4*)src)[1];
  uint4 pk;
  pk.x = (unsigned)f2bf(f0.x) | ((unsigned)f2bf(f0.y) << 16);
  pk.y = (unsigned)f2bf(f0.z) | ((unsigned)f2bf(f0.w) << 16);
  pk.z = (unsigned)f2bf(f1.x) | ((unsigned)f2bf(f1.y) << 16);
  pk.w = (unsigned)f2bf(f1.z) | ((unsigned)f2bf(f1.w) << 16);
  *(uint4*)(xe + ((size_t)t * BB + b) * EE + lane * 8) = pk;
}

// ---------------- kernel 2: persistent LSTM recurrence (R6 + 16B coalesced h-stores) --------
// 128 WGs x 256 threads. WG w owns h indices [w*8, w*8+8): 32 rows of [W_ih|W_hh] in LDS.
// Barrier: spread flags (1/64B line), sc0sc1 stores, ONE polling wave per WG, s_sleep backoff.
// h(t+1) write-out: per batch row, the WG's 8 columns = 16 contiguous bytes -> gathered via
// 3x shfl_xor into lane c15==0 and stored as ONE global_store_dwordx4 (64 stores/WG vs 256).
template <bool FULLT>
__global__ __launch_bounds__(256, 1) void k_lstm(const float* __restrict__ W_ih,
                                                 const float* __restrict__ W_hh,
                                                 const float* __restrict__ b_ih,
                                                 const float* __restrict__ b_hh,
                                                 const unsigned short* __restrict__ xe,
                                                 unsigned short* __restrict__ hbuf,
                                                 float* __restrict__ feat,
                                                 int* __restrict__ sync) {
  __shared__ unsigned short Wlds[32][1544];  // stride 772 words = 4 banks mod 32
  __shared__ float bias_lds[32];

  const int w = blockIdx.x;
  const int tid = threadIdx.x;
  unsigned int* sy = (unsigned int*)sync;

  for (int idx = tid; idx < 32 * 512; idx += 256) {
    int r = idx >> 9, k = idx & 511;
    int R = (r >> 3) * 1024 + w * 8 + (r & 7);
    Wlds[r][k] = f2bf(W_ih[(size_t)R * EE + k]);
  }
  for (int idx = tid; idx < 32 * 1024; idx += 256) {
    int r = idx >> 10, k = idx & 1023;
    int R = (r >> 3) * 1024 + w * 8 + (r & 7);
    Wlds[r][512 + k] = f2bf(W_hh[(size_t)R * HH + k]);
  }
  if (tid < 32) {
    int R = (tid >> 3) * 1024 + w * 8 + (tid & 7);
    bias_lds[tid] = b_ih[R] + b_hh[R];
  }
  __syncthreads();

  // One-time wholesale acquire invalidate: drop stale/poisoned clean cache lines.
  { int dummy = 0; (void)__hip_atomic_load(&dummy, __ATOMIC_ACQUIRE, __HIP_MEMORY_SCOPE_SYSTEM); }
  __syncthreads();

  const int lane = tid & 63;
  const int wm = tid >> 6;
  const int c15 = lane & 15;
  const int kq = lane >> 4;
  const int k0 = kq * 8;
  const int bA = wm * 16 + c15;

  const unsigned short* wl0 = &Wlds[c15][k0];
  const unsigned short* wl1 = &Wlds[16 + c15][k0];
  const float bias0 = bias_lds[c15];
  const float bias1 = bias_lds[16 + c15];

  float cst[4]  = {0.f, 0.f, 0.f, 0.f};
  float hmax[4] = {-1e30f, -1e30f, -1e30f, -1e30f};

  const size_t xe_lane = (size_t)bA * EE + k0;
  const size_t h_lane  = (size_t)bA * HH + k0;
  // spread flags: flag[w] at sy[16*w] (64B apart)
  const unsigned int* q0 = sy + 16 * lane;
  const unsigned int* q1 = sy + 16 * (lane + 64);

  for (int t = 0; t < TT; ++t) {
    facc a0 = {0.f,0.f,0.f,0.f}, a1 = a0, a2 = a0, a3 = a0;
    const unsigned short* xet = xe + (size_t)t * (BB * EE) + xe_lane;

    // ---- xe-part (h-independent): overlaps producers' flag propagation ----
#pragma unroll 4
    for (int kk = 0; kk < 16; kk += 2) {
      bfrag A  = *(const bfrag*)(xet + kk * 32);
      bfrag B0 = *(const bfrag*)(wl0 + kk * 32);
      bfrag B1 = *(const bfrag*)(wl1 + kk * 32);
      a0 = __builtin_amdgcn_mfma_f32_16x16x32_bf16(A, B0, a0, 0, 0, 0);
      a2 = __builtin_amdgcn_mfma_f32_16x16x32_bf16(A, B1, a2, 0, 0, 0);
      bfrag A2  = *(const bfrag*)(xet + kk * 32 + 32);
      bfrag B0b = *(const bfrag*)(wl0 + kk * 32 + 32);
      bfrag B1b = *(const bfrag*)(wl1 + kk * 32 + 32);
      a1 = __builtin_amdgcn_mfma_f32_16x16x32_bf16(A2, B0b, a1, 0, 0, 0);
      a3 = __builtin_amdgcn_mfma_f32_16x16x32_bf16(A2, B1b, a3, 0, 0, 0);
    }

    if (t > 0) {
      // ---- barrier wait: wave0 only, spread lines, s_sleep backoff ----
      if (tid < 64) {
        unsigned int fa, fb;
        for (;;) {
          ld2_u32_sys(q0, q1, fa, fb);
          if (!__any((int)(min(fa, fb) < (unsigned)t))) break;
          __builtin_amdgcn_s_sleep(2);
        }
      }
      __syncthreads();

      if constexpr (FULLT) {
        const unsigned short* hp = hbuf + (size_t)t * (BB * HH) + h_lane;
#pragma unroll 4
        for (int kk = 0; kk < 32; kk += 2) {
          bfrag A  = *(const bfrag*)(hp + kk * 32);
          bfrag B0 = *(const bfrag*)(wl0 + 512 + kk * 32);
          bfrag B1 = *(const bfrag*)(wl1 + 512 + kk * 32);
          a0 = __builtin_amdgcn_mfma_f32_16x16x32_bf16(A, B0, a0, 0, 0, 0);
          a2 = __builtin_amdgcn_mfma_f32_16x16x32_bf16(A, B1, a2, 0, 0, 0);
          bfrag A2  = *(const bfrag*)(hp + (kk + 1) * 32);
          bfrag B0b = *(const bfrag*)(wl0 + 512 + (kk + 1) * 32);
          bfrag B1b = *(const bfrag*)(wl1 + 512 + (kk + 1) * 32);
          a1 = __builtin_amdgcn_mfma_f32_16x16x32_bf16(A2, B0b, a1, 0, 0, 0);
          a3 = __builtin_amdgcn_mfma_f32_16x16x32_bf16(A2, B1b, a3, 0, 0, 0);
        }
      } else {
        const unsigned short* hp = hbuf + ((t & 1) ? (size_t)(BB * HH) : 0) + h_lane;
        bfrag hA[32];
#pragma unroll
        for (int i = 0; i < 32; ++i)
          asm volatile("global_load_dwordx4 %0, %1, off sc0 sc1"
                       : "=v"(hA[i]) : "v"(hp + i * 32));
        __builtin_amdgcn_sched_barrier(0);
        asm volatile("s_waitcnt vmcnt(0)" ::: "memory");
        __builtin_amdgcn_sched_barrier(0);
#pragma unroll
        for (int kk = 0; kk < 32; kk += 2) {
          bfrag B0 = *(const bfrag*)(wl0 + 512 + kk * 32);
          bfrag B1 = *(const bfrag*)(wl1 + 512 + kk * 32);
          a0 = __builtin_amdgcn_mfma_f32_16x16x32_bf16(hA[kk], B0, a0, 0, 0, 0);
          a2 = __builtin_amdgcn_mfma_f32_16x16x32_bf16(hA[kk], B1, a2, 0, 0, 0);
          bfrag B0b = *(const bfrag*)(wl0 + 512 + (kk + 1) * 32);
          bfrag B1b = *(const bfrag*)(wl1 + 512 + (kk + 1) * 32);
          a1 = __builtin_amdgcn_mfma_f32_16x16x32_bf16(hA[kk + 1], B0b, a1, 0, 0, 0);
          a3 = __builtin_amdgcn_mfma_f32_16x16x32_bf16(hA[kk + 1], B1b, a3, 0, 0, 0);
        }
      }
    }

    facc X = a0 + a1;
    facc Y = a2 + a3;
    unsigned int hb[4];
#pragma unroll
    for (int j = 0; j < 4; ++j) {
      float xv = X[j] + bias0;
      float yv = Y[j] + bias1;
      float xs = __shfl_xor(xv, 8, 64);
      float ys = __shfl_xor(yv, 8, 64);
      bool lo = (c15 < 8);
      float vi = lo ? xv : xs;
      float vf = lo ? xs : xv;
      float vg = lo ? yv : ys;
      float vo = lo ? ys : yv;
      float sf = 1.f / (1.f + __expf(-vf));
      float si = 1.f / (1.f + __expf(-vi));
      float eg = __expf(-2.f * fabsf(vg));
      float tg = copysignf((1.f - eg) / (1.f + eg), vg);
      float cc = sf * cst[j] + si * tg;
      cst[j] = cc;
      float so = 1.f / (1.f + __expf(-vo));
      float ec = __expf(-2.f * fabsf(cc));
      float tc = copysignf((1.f - ec) / (1.f + ec), cc);
      float hh = so * tc;
      hmax[j] = fmaxf(hmax[j], hh);
      hb[j] = f2bf(hh);
    }

    if (t < TT - 1) {
      // ---- coalesced h(t+1) store: gather 8 cols into lane c15==0, one dwordx4 ----
      unsigned short* hball;
      if constexpr (FULLT)
        hball = hbuf + (size_t)(t + 1) * (BB * HH);
      else
        hball = hbuf + ((t & 1) ? 0 : (size_t)(BB * HH));
      u32x4* hn16 = (u32x4*)hball;
#pragma unroll
      for (int j = 0; j < 4; ++j) {
        unsigned int part = (unsigned int)__shfl_xor((int)hb[j], 1, 64);
        unsigned int v01 = (hb[j] & 0xffffu) | (part << 16);     // cols (c15, c15+1) at even c15
        unsigned int v23 = (unsigned int)__shfl_xor((int)v01, 2, 64);
        unsigned int v45 = (unsigned int)__shfl_xor((int)v01, 4, 64);
        unsigned int v67 = (unsigned int)__shfl_xor((int)v23, 4, 64);
        if (c15 == 0) {
          u32x4 q = { v01, v23, v45, v67 };                      // cols 0..7 of row b
          u32x4* p = hn16 + (size_t)(wm * 16 + kq * 4 + j) * (HH / 8) + w;
          st_u32x4_sys(p, q);
        }
      }
      asm volatile("s_waitcnt vmcnt(0)" ::: "memory");  // h at MALL before flag
      __syncthreads();
      if (tid == 0) st_u32_sys(sy + 16 * w, (unsigned)(t + 1));  // spread flag
    }
  }

  if (c15 < 8) {
    int jh = w * 8 + c15;
#pragma unroll
    for (int j = 0; j < 4; ++j)
      feat[(size_t)(wm * 16 + kq * 4 + j) * HH + jh] = hmax[j];
  }
}

// ---------------- kernel 3: tiny FC ----------------
__global__ __launch_bounds__(64) void k_fc(const float* __restrict__ feat,
                                           const float* __restrict__ W_fc,
                                           const float* __restrict__ b_fc,
                                           float* __restrict__ out) {
  int b = blockIdx.x, cls = blockIdx.y;
  int lane = threadIdx.x;
  const float* f  = feat + (size_t)b * HH;
  const float* wr = W_fc + (size_t)cls * HH;
  float s = 0.f;
  for (int k = lane; k < HH; k += 64) s = fmaf(f[k], wr[k], s);
#pragma unroll
  for (int off = 32; off > 0; off >>= 1) s += __shfl_down(s, off, 64);
  if (lane == 0) out[b * NCLS + cls] = s + b_fc[cls];
}

extern "C" void kernel_launch(void* const* d_in, const int* in_sizes, int n_in,
                              void* d_out, int out_size, void* d_ws, size_t ws_size,
                              hipStream_t stream) {
  const int*   x    = (const int*)d_in[0];
  const float* emb  = (const float*)d_in[1];
  const float* W_ih = (const float*)d_in[2];
  const float* W_hh = (const float*)d_in[3];
  const float* b_ih = (const float*)d_in[4];
  const float* b_hh = (const float*)d_in[5];
  const float* W_fc = (const float*)d_in[6];
  const float* b_fc = (const float*)d_in[7];
  float* out = (float*)d_out;

  char* ws = (char*)d_ws;
  unsigned short* xe   = (unsigned short*)(ws);
  float*          feat = (float*)(ws + XE_BYTES);
  int*            sync = (int*)(ws + XE_BYTES + FEAT_BYTES);
  unsigned short* hbuf = (unsigned short*)(ws + XE_BYTES + FEAT_BYTES + SYNC_BYTES);

  const size_t base = XE_BYTES + FEAT_BYTES + SYNC_BYTES;
  const bool full = (ws_size >= base + HBUF_FULL);

  k_gather<<<dim3(8192), dim3(256), 0, stream>>>(x, emb, xe, sync);
  if (full)
    k_lstm<true><<<dim3(NWG), dim3(256), 0, stream>>>(W_ih, W_hh, b_ih, b_hh, xe, hbuf, feat, sync);
  else
    k_lstm<false><<<dim3(NWG), dim3(256), 0, stream>>>(W_ih, W_hh, b_ih, b_hh, xe, hbuf, feat, sync);
  k_fc<<<dim3(BB, NCLS), dim3(64), 0, stream>>>(feat, W_fc, b_fc, out);
}